// Round 4
// baseline (19808.994 us; speedup 1.0000x reference)
//
#include <hip/hip_runtime.h>
#include <hip/hip_bf16.h>

typedef __bf16 bf16x8 __attribute__((ext_vector_type(8)));
typedef float f32x4 __attribute__((ext_vector_type(4)));

#define MFMA16(a, b, c) __builtin_amdgcn_mfma_f32_16x16x32_bf16((a), (b), (c), 0, 0, 0)

#define BB 64
#define TT 256
#define II 512
#define SS 256
#define DD 1024
#define HH 1024

// ---- workspace layout (bytes); total need = 43,024,388 ---------------------
#define OFF_A ((size_t)0)            // 32MB bf16 activation slot (a0/a2)
#define OFF_Z ((size_t)33554432)     // 8MB bf16 z archive (T,B,S)
#define OFF_HB32 ((size_t)41943040)  // f32 [2][64][1024] h carry
#define OFF_HB16 ((size_t)42467328)  // bf16 [2][64][1024]
#define OFF_ZC ((size_t)42729472)    // bf16 [64][256] z carry
#define OFF_SH ((size_t)42762240)    // 128KB h_all spill rows
#define OFF_SA ((size_t)42893312)    // 128KB a1 spill rows
#define OFF_FLAG ((size_t)43024384)  // dtype flag: 1=bf16, 0=fp32

#define A0_DOUT_BYTE 33423360  // fp32 world: a0 scratch byte offset inside d_out
#define OUTD_ELEMS 8355840     // 64*255*512

template <typename T>
struct Cut {  // rows of stride-1024-bf16 fitting the d_out scratch region
  static constexpr int rows = (sizeof(T) == 2) ? 16352 : 16320;
};

__device__ __forceinline__ float fsig(float x) { return 1.f / (1.f + __expf(-x)); }
__device__ __forceinline__ float ftanh(float x) {
  float ax = __builtin_fabsf(x);
  float e = __expf(-2.f * ax);
  float r = (1.f - e) / (1.f + e);
  return __builtin_copysignf(r, x);
}

// load 8 contiguous elements as bf16x8, converting if source is fp32
template <typename T>
__device__ __forceinline__ bf16x8 ld8(const T* p) {
  if constexpr (sizeof(T) == 2) {
    return *(const bf16x8*)p;
  } else {
    float4 a = *(const float4*)p;
    float4 b = *(const float4*)(p + 4);
    bf16x8 r;
    r[0] = (__bf16)a.x; r[1] = (__bf16)a.y; r[2] = (__bf16)a.z; r[3] = (__bf16)a.w;
    r[4] = (__bf16)b.x; r[5] = (__bf16)b.y; r[6] = (__bf16)b.z; r[7] = (__bf16)b.w;
    return r;
  }
}

__device__ __forceinline__ const __bf16* rp_c(const __bf16* b, const __bf16* s, int m, int cut) {
  return (m < cut) ? b + (size_t)m * 1024 : s + (size_t)(m - cut) * 1024;
}
__device__ __forceinline__ __bf16* rp_w(__bf16* b, __bf16* s, int m, int cut) {
  return (m < cut) ? b + (size_t)m * 1024 : s + (size_t)(m - cut) * 1024;
}

// ---------------------------------------------------------------------------
// dtype detector: bf16 data -> low half-word of each u32 has a mid-range
// exponent field; fp32 data -> low half-word is uniform mantissa bits.
// Deterministic for fixed inputs => graph-capture safe.
// ---------------------------------------------------------------------------
__global__ void k_detect(const void* __restrict__ x, char* __restrict__ ws) {
  if (threadIdx.x == 0) {
    const unsigned* u = (const unsigned*)x;
    int hits = 0;
    for (int i = 0; i < 64; ++i) {
      unsigned ex = (u[i] >> 7) & 0xFFu;
      hits += (ex >= 100u && ex <= 145u) ? 1 : 0;
    }
    *(int*)(ws + OFF_FLAG) = (hits >= 32) ? 1 : 0;
  }
}

// ---------------------------------------------------------------------------
// GRU step t: h_t = gru(z_{t-1}, h_{t-1}); 64 blocks x 16 h-cols
// ---------------------------------------------------------------------------
template <typename T>
__device__ __forceinline__ void gru_impl(const T* Wih, const T* Whh, const T* bih, const T* bhh,
                                         char* ws, char* doutc, int t) {
  int blk = blockIdx.x, tid = threadIdx.x, lane = tid & 63, wv = tid >> 6;
  int n15 = lane & 15, q8 = (lane >> 4) * 8, q4 = (lane >> 4) * 4;
  int c0 = blk * 16, cc = c0 + n15;
  const int rb = wv * 16 + n15;

  const __bf16* h_in16 = (const __bf16*)(ws + OFF_HB16) + (size_t)(t & 1) * BB * DD;
  __bf16* h_out16 = (__bf16*)(ws + OFF_HB16) + (size_t)((t + 1) & 1) * BB * DD;
  const float* h_in32 = (const float*)(ws + OFF_HB32) + (size_t)(t & 1) * BB * DD;
  float* h_out32 = (float*)(ws + OFF_HB32) + (size_t)((t + 1) & 1) * BB * DD;
  const __bf16* z_in = (const __bf16*)(ws + OFF_ZC);
  __bf16* hall = (__bf16*)doutc;
  __bf16* hallS = (__bf16*)(ws + OFF_SH);

  const T* whr = Whh + (size_t)(c0 + n15) * DD + q8;
  const T* whz = Whh + (size_t)(DD + c0 + n15) * DD + q8;
  const T* whn = Whh + (size_t)(2 * DD + c0 + n15) * DD + q8;
  const T* wir = Wih + (size_t)(c0 + n15) * SS + q8;
  const T* wiz = Wih + (size_t)(DD + c0 + n15) * SS + q8;
  const T* win = Wih + (size_t)(2 * DD + c0 + n15) * SS + q8;

  f32x4 accr = {}, accz = {}, acchn = {}, accin = {};
  if (t > 0) {
    const __bf16* aptr = h_in16 + (size_t)rb * DD + q8;
#pragma unroll 4
    for (int kk = 0; kk < 32; ++kk) {
      bf16x8 a = *(const bf16x8*)(aptr + kk * 32);
      accr = MFMA16(a, ld8(whr + kk * 32), accr);
      accz = MFMA16(a, ld8(whz + kk * 32), accz);
      acchn = MFMA16(a, ld8(whn + kk * 32), acchn);
    }
    const __bf16* zptr = z_in + (size_t)rb * SS + q8;
#pragma unroll 4
    for (int kk = 0; kk < 8; ++kk) {
      bf16x8 a = *(const bf16x8*)(zptr + kk * 32);
      accr = MFMA16(a, ld8(wir + kk * 32), accr);
      accz = MFMA16(a, ld8(wiz + kk * 32), accz);
      accin = MFMA16(a, ld8(win + kk * 32), accin);
    }
  }
  float brs = (float)bih[cc] + (float)bhh[cc];
  float bzs = (float)bih[DD + cc] + (float)bhh[DD + cc];
  float bin = (float)bih[2 * DD + cc];
  float bhn = (float)bhh[2 * DD + cc];

  int mb = wv * 16 + q4;
#pragma unroll
  for (int r = 0; r < 4; ++r) {
    int mm = mb + r;
    float rg = fsig(accr[r] + brs);
    float zg = fsig(accz[r] + bzs);
    float ng = ftanh(accin[r] + bin + rg * (acchn[r] + bhn));
    float ho = (t > 0) ? h_in32[mm * DD + cc] : 0.f;
    float hn = (1.f - zg) * ng + zg * ho;
    h_out32[mm * DD + cc] = hn;
    __bf16 hbv = (__bf16)hn;
    h_out16[mm * DD + cc] = hbv;
    rp_w(hall, hallS, t * 64 + mm, Cut<T>::rows)[cc] = hbv;
  }
}

// ---------------------------------------------------------------------------
// Posterior step t: z_t = noise_t * exp(0.5*([x_t|h_t]@Wv.T+bv)) + [x_t|h_t]@Wm.T+bm
// 16 blocks x 16 z-cols; x-part recomputed here (K=512) - no xm/xv scratch.
// ---------------------------------------------------------------------------
template <typename T>
__device__ __forceinline__ void post_impl(const T* Wm, const T* bm, const T* Wv, const T* bv,
                                          const T* noise, const T* x, char* ws, int t) {
  int p = blockIdx.x, tid = threadIdx.x, lane = tid & 63, wv = tid >> 6;
  int n15 = lane & 15, q8 = (lane >> 4) * 8, q4 = (lane >> 4) * 4;
  int c2 = p * 16 + n15;
  const int rb = wv * 16 + n15;

  const __bf16* h16 = (const __bf16*)(ws + OFF_HB16) + (size_t)((t + 1) & 1) * BB * DD;
  __bf16* z_cur = (__bf16*)(ws + OFF_ZC);
  __bf16* z_all = (__bf16*)(ws + OFF_Z);

  const T* wmh = Wm + (size_t)c2 * (II + DD) + II + q8;
  const T* wvh = Wv + (size_t)c2 * (II + DD) + II + q8;
  const T* wmx = Wm + (size_t)c2 * (II + DD) + q8;
  const T* wvx = Wv + (size_t)c2 * (II + DD) + q8;

  f32x4 am = {}, av = {};
  const __bf16* hptr = h16 + (size_t)rb * DD + q8;
#pragma unroll 4
  for (int kk = 0; kk < 32; ++kk) {
    bf16x8 a = *(const bf16x8*)(hptr + kk * 32);
    am = MFMA16(a, ld8(wmh + kk * 32), am);
    av = MFMA16(a, ld8(wvh + kk * 32), av);
  }
  const T* xp = x + ((size_t)rb * TT + t) * II + q8;  // x[b, t, :]
#pragma unroll 4
  for (int kk = 0; kk < 16; ++kk) {
    bf16x8 a = ld8(xp + kk * 32);
    am = MFMA16(a, ld8(wmx + kk * 32), am);
    av = MFMA16(a, ld8(wvx + kk * 32), av);
  }
  float bmv = (float)bm[c2], bvv = (float)bv[c2];
  const T* noise_t = noise + (size_t)t * BB * SS;
  int mb = wv * 16 + q4;
#pragma unroll
  for (int r = 0; r < 4; ++r) {
    int mm = mb + r;
    int li = mm * SS + c2;
    float mean = am[r] + bmv;
    float sd = __expf(0.5f * (av[r] + bvv));
    float zt = (float)noise_t[li] * sd + mean;
    __bf16 zb = (__bf16)zt;
    z_cur[li] = zb;
    z_all[(size_t)t * BB * SS + li] = zb;
  }
}

// ---------------------------------------------------------------------------
// Decoder layer 0: elu([h_all|z_all] @ W0.T + b0) -> a0
// ---------------------------------------------------------------------------
template <typename T>
__device__ __forceinline__ void dec0_impl(const T* W0, const T* b0, char* ws, char* doutc) {
  const __bf16* z_all = (const __bf16*)(ws + OFF_Z);
  const __bf16* hall = (const __bf16*)doutc;
  const __bf16* hallS = (const __bf16*)(ws + OFF_SH);
  __bf16* C = (sizeof(T) == 2) ? (__bf16*)(ws + OFF_A) : (__bf16*)(doutc + A0_DOUT_BYTE);

  int m0 = blockIdx.x * 128, n0 = blockIdx.y * 128;
  int tid = threadIdx.x, lane = tid & 63, w = tid >> 6;
  int wm = w >> 1, wn = w & 1;
  int n15 = lane & 15, q8 = (lane >> 4) * 8, q4 = (lane >> 4) * 4;

  const __bf16* hrow[4];
  const __bf16* zrow[4];
  const T* brow[4];
#pragma unroll
  for (int i = 0; i < 4; ++i) {
    int row = m0 + wm * 64 + i * 16 + n15;  // m = b*256 + t
    int b = row >> 8, tq = row & 255;
    hrow[i] = rp_c(hall, hallS, tq * 64 + b, Cut<T>::rows) + q8;
    zrow[i] = z_all + ((size_t)tq * BB + b) * SS + q8;
  }
#pragma unroll
  for (int j = 0; j < 4; ++j)
    brow[j] = W0 + (size_t)(n0 + wn * 64 + j * 16 + n15) * (DD + SS) + q8;

  f32x4 acc[4][4] = {};
  for (int k = 0; k < DD + SS; k += 32) {
    bf16x8 af[4], bfv[4];
#pragma unroll
    for (int i = 0; i < 4; ++i)
      af[i] = (k < DD) ? *(const bf16x8*)(hrow[i] + k) : *(const bf16x8*)(zrow[i] + k - DD);
#pragma unroll
    for (int j = 0; j < 4; ++j) bfv[j] = ld8(brow[j] + k);
#pragma unroll
    for (int i = 0; i < 4; ++i)
#pragma unroll
      for (int j = 0; j < 4; ++j) acc[i][j] = MFMA16(af[i], bfv[j], acc[i][j]);
  }
#pragma unroll
  for (int i = 0; i < 4; ++i) {
    int mr = m0 + wm * 64 + i * 16 + q4;
#pragma unroll
    for (int j = 0; j < 4; ++j) {
      int c = n0 + wn * 64 + j * 16 + n15;
      float bb = (float)b0[c];
#pragma unroll
      for (int r = 0; r < 4; ++r) {
        float v = acc[i][j][r] + bb;
        v = v > 0.f ? v : (__expf(v) - 1.f);
        C[(size_t)(mr + r) * HH + c] = (__bf16)v;
      }
    }
  }
}

// ---------------------------------------------------------------------------
// Decoder mid layers: stage 1 = a0->a1, stage 2 = a1->a2
// ---------------------------------------------------------------------------
template <typename T>
__device__ __forceinline__ void decmid_impl(const T* W, const T* bias, char* ws, char* doutc,
                                            int stage) {
  const __bf16* a0 = (sizeof(T) == 2) ? (const __bf16*)(ws + OFF_A)
                                      : (const __bf16*)(doutc + A0_DOUT_BYTE);
  const __bf16 *Ab, *As;
  __bf16 *Cb, *Cs;
  int cutA, cutC;
  if (stage == 1) {
    Ab = a0; As = a0; cutA = 1 << 28;                       // contiguous
    Cb = (__bf16*)doutc; Cs = (__bf16*)(ws + OFF_SA); cutC = Cut<T>::rows;
  } else {
    Ab = (const __bf16*)doutc; As = (const __bf16*)(ws + OFF_SA); cutA = Cut<T>::rows;
    Cb = (__bf16*)(ws + OFF_A); Cs = (__bf16*)(ws + OFF_A); cutC = 1 << 28;
  }

  int m0 = blockIdx.x * 128, n0 = blockIdx.y * 128;
  int tid = threadIdx.x, lane = tid & 63, w = tid >> 6;
  int wm = w >> 1, wn = w & 1;
  int n15 = lane & 15, q8 = (lane >> 4) * 8, q4 = (lane >> 4) * 4;

  const __bf16* arow[4];
  const T* brow[4];
#pragma unroll
  for (int i = 0; i < 4; ++i) arow[i] = rp_c(Ab, As, m0 + wm * 64 + i * 16 + n15, cutA) + q8;
#pragma unroll
  for (int j = 0; j < 4; ++j) brow[j] = W + (size_t)(n0 + wn * 64 + j * 16 + n15) * DD + q8;

  f32x4 acc[4][4] = {};
  for (int k = 0; k < DD; k += 32) {
    bf16x8 af[4], bfv[4];
#pragma unroll
    for (int i = 0; i < 4; ++i) af[i] = *(const bf16x8*)(arow[i] + k);
#pragma unroll
    for (int j = 0; j < 4; ++j) bfv[j] = ld8(brow[j] + k);
#pragma unroll
    for (int i = 0; i < 4; ++i)
#pragma unroll
      for (int j = 0; j < 4; ++j) acc[i][j] = MFMA16(af[i], bfv[j], acc[i][j]);
  }
#pragma unroll
  for (int i = 0; i < 4; ++i) {
    int mr = m0 + wm * 64 + i * 16 + q4;
#pragma unroll
    for (int j = 0; j < 4; ++j) {
      int c = n0 + wn * 64 + j * 16 + n15;
      float bb = (float)bias[c];
#pragma unroll
      for (int r = 0; r < 4; ++r) {
        float v = acc[i][j][r] + bb;
        v = v > 0.f ? v : (__expf(v) - 1.f);
        rp_w(Cb, Cs, mr + r, cutC)[c] = (__bf16)v;
      }
    }
  }
}

// ---------------------------------------------------------------------------
// Decoder layer 3 + output assembly
// ---------------------------------------------------------------------------
template <typename T>
__device__ __forceinline__ void dec3_impl(const T* W3, const T* b3, const T* x, char* ws,
                                          char* doutc) {
  const __bf16* A = (const __bf16*)(ws + OFF_A);
  T* outd = (T*)doutc;
  T* outh = (T*)doutc + OUTD_ELEMS;

  int m0 = blockIdx.x * 128, n0 = blockIdx.y * 128;
  int tid = threadIdx.x, lane = tid & 63, w = tid >> 6;
  int wm = w >> 1, wn = w & 1;
  int n15 = lane & 15, q8 = (lane >> 4) * 8, q4 = (lane >> 4) * 4;

  const __bf16* arow[4];
  const T* brow[4];
#pragma unroll
  for (int i = 0; i < 4; ++i) arow[i] = A + (size_t)(m0 + wm * 64 + i * 16 + n15) * HH + q8;
#pragma unroll
  for (int j = 0; j < 4; ++j) brow[j] = W3 + (size_t)(n0 + wn * 64 + j * 16 + n15) * HH + q8;

  f32x4 acc[4][4] = {};
  for (int k = 0; k < HH; k += 32) {
    bf16x8 af[4], bfv[4];
#pragma unroll
    for (int i = 0; i < 4; ++i) af[i] = *(const bf16x8*)(arow[i] + k);
#pragma unroll
    for (int j = 0; j < 4; ++j) bfv[j] = ld8(brow[j] + k);
#pragma unroll
    for (int i = 0; i < 4; ++i)
#pragma unroll
      for (int j = 0; j < 4; ++j) acc[i][j] = MFMA16(af[i], bfv[j], acc[i][j]);
  }
#pragma unroll
  for (int i = 0; i < 4; ++i) {
    int mr = m0 + wm * 64 + i * 16 + q4;
#pragma unroll
    for (int j = 0; j < 4; ++j) {
      int c = n0 + wn * 64 + j * 16 + n15;
      float b3v = (float)b3[c];
#pragma unroll
      for (int r = 0; r < 4; ++r) {
        int mm = mr + r;
        int b = mm >> 8, tq = mm & 255;
        float dv = acc[i][j][r] + b3v;
        if (tq < 255) {
          outd[((size_t)b * 255 + tq) * II + c] = (T)dv;
          float xval = (float)x[((size_t)b * TT + tq) * II + c];
          outh[((size_t)b * TT + tq + 1) * II + c] = (T)(xval + dv);
        }
        if (tq == 0) outh[((size_t)b * TT) * II + c] = (T)(float)x[((size_t)b * TT) * II + c];
      }
    }
  }
}

// ---------------------------------------------------------------------------
// flag-dispatching wrappers
// ---------------------------------------------------------------------------
#define FLAG_OF(ws) (*(const int*)((ws) + OFF_FLAG))

__global__ __launch_bounds__(256) void k_gru(const void* Wih, const void* Whh, const void* bih,
                                             const void* bhh, char* ws, char* doutc, int t) {
  if (FLAG_OF(ws))
    gru_impl<__bf16>((const __bf16*)Wih, (const __bf16*)Whh, (const __bf16*)bih,
                     (const __bf16*)bhh, ws, doutc, t);
  else
    gru_impl<float>((const float*)Wih, (const float*)Whh, (const float*)bih, (const float*)bhh,
                    ws, doutc, t);
}

__global__ __launch_bounds__(256) void k_post(const void* Wm, const void* bm, const void* Wv,
                                              const void* bv, const void* noise, const void* x,
                                              char* ws, int t) {
  if (FLAG_OF(ws))
    post_impl<__bf16>((const __bf16*)Wm, (const __bf16*)bm, (const __bf16*)Wv, (const __bf16*)bv,
                      (const __bf16*)noise, (const __bf16*)x, ws, t);
  else
    post_impl<float>((const float*)Wm, (const float*)bm, (const float*)Wv, (const float*)bv,
                     (const float*)noise, (const float*)x, ws, t);
}

__global__ __launch_bounds__(256) void k_dec0(const void* W0, const void* b0, char* ws,
                                              char* doutc) {
  if (FLAG_OF(ws))
    dec0_impl<__bf16>((const __bf16*)W0, (const __bf16*)b0, ws, doutc);
  else
    dec0_impl<float>((const float*)W0, (const float*)b0, ws, doutc);
}

__global__ __launch_bounds__(256) void k_dec_mid(const void* W, const void* bias, char* ws,
                                                 char* doutc, int stage) {
  if (FLAG_OF(ws))
    decmid_impl<__bf16>((const __bf16*)W, (const __bf16*)bias, ws, doutc, stage);
  else
    decmid_impl<float>((const float*)W, (const float*)bias, ws, doutc, stage);
}

__global__ __launch_bounds__(256) void k_dec3(const void* W3, const void* b3, const void* x,
                                              char* ws, char* doutc) {
  if (FLAG_OF(ws))
    dec3_impl<__bf16>((const __bf16*)W3, (const __bf16*)b3, (const __bf16*)x, ws, doutc);
  else
    dec3_impl<float>((const float*)W3, (const float*)b3, (const float*)x, ws, doutc);
}

// ---------------------------------------------------------------------------
extern "C" void kernel_launch(void* const* d_in, const int* in_sizes, int n_in,
                              void* d_out, int out_size, void* d_ws, size_t ws_size,
                              hipStream_t stream) {
  const void* x = d_in[0];
  const void* noise = d_in[1];
  const void* W_ih = d_in[2];
  const void* W_hh = d_in[3];
  const void* b_ih = d_in[4];
  const void* b_hh = d_in[5];
  const void* Wm = d_in[6];
  const void* bm = d_in[7];
  const void* Wv = d_in[8];
  const void* bv = d_in[9];
  const void* dW0 = d_in[10];
  const void* db0 = d_in[11];
  const void* dW1 = d_in[12];
  const void* db1 = d_in[13];
  const void* dW2 = d_in[14];
  const void* db2 = d_in[15];
  const void* dW3 = d_in[16];
  const void* db3 = d_in[17];

  char* ws = (char*)d_ws;
  char* doutc = (char*)d_out;

  // 0) detect input dtype (bf16 vs fp32) from x's bit patterns
  k_detect<<<1, 64, 0, stream>>>(x, ws);

  // 1) sequential scan: 2 launches per step (hardware-coherent boundaries)
  for (int t = 0; t < TT; ++t) {
    k_gru<<<64, 256, 0, stream>>>(W_ih, W_hh, b_ih, b_hh, ws, doutc, t);
    k_post<<<16, 256, 0, stream>>>(Wm, bm, Wv, bv, noise, x, ws, t);
  }

  // 2) decoder
  k_dec0<<<dim3(128, 8), 256, 0, stream>>>(dW0, db0, ws, doutc);
  k_dec_mid<<<dim3(128, 8), 256, 0, stream>>>(dW1, db1, ws, doutc, 1);
  k_dec_mid<<<dim3(128, 8), 256, 0, stream>>>(dW2, db2, ws, doutc, 2);
  k_dec3<<<dim3(128, 4), 256, 0, stream>>>(dW3, db3, x, ws, doutc);
}

// Round 5
// 11636.011 us; speedup vs baseline: 1.7024x; 1.7024x over previous
//
#include <hip/hip_runtime.h>
#include <hip/hip_bf16.h>

typedef __bf16 bf16x8 __attribute__((ext_vector_type(8)));
typedef float f32x4 __attribute__((ext_vector_type(4)));

#define MFMA16(a, b, c) __builtin_amdgcn_mfma_f32_16x16x32_bf16((a), (b), (c), 0, 0, 0)

#define BB 64
#define TT 256
#define II 512
#define SS 256
#define DD 1024
#define HH 1024

// ---- ws layout (bytes); total 42,764,288 <= 43,024,388 proven --------------
#define OFF_A ((size_t)0)            // 32MB bf16 activation slot (a0, then a2)
#define OFF_Z ((size_t)33554432)     // 8MB bf16 z archive (T,B,S)
#define OFF_HB32 ((size_t)41943040)  // f32 [2][64][1024] h carry
#define OFF_HB16 ((size_t)42467328)  // bf16 [2][64][1024]
#define OFF_ZC ((size_t)42729472)    // bf16 [64][256] z carry
#define OFF_CNT ((size_t)42762240)   // int hcnt[256] | zcnt[256]

// ---- d_out (fp32, 66,977,792 B) scratch layout -----------------------------
// [0,32MB): h_all bf16 rows (t*64+b)*1024    (dead after dec0 -> a1 bf16)
// [34MB,42MB): xm bf16 (T,B,S)   [42MB,50MB): xv bf16 (T,B,S)  (dead after scan)
#define DO_XM ((size_t)35651584)
#define DO_XV ((size_t)44040192)
#define OUTD_ELEMS 8355840  // 64*255*512

__device__ __forceinline__ float fsig(float x) { return 1.f / (1.f + __expf(-x)); }
__device__ __forceinline__ float ftanh(float x) {
  float ax = __builtin_fabsf(x);
  float e = __expf(-2.f * ax);
  float r = (1.f - e) / (1.f + e);
  return __builtin_copysignf(r, x);
}

// 8 fp32 -> bf16x8 (proven round 4)
__device__ __forceinline__ bf16x8 ld8f(const float* p) {
  float4 a = *(const float4*)p;
  float4 b = *(const float4*)(p + 4);
  bf16x8 r;
  r[0] = (__bf16)a.x; r[1] = (__bf16)a.y; r[2] = (__bf16)a.z; r[3] = (__bf16)a.w;
  r[4] = (__bf16)b.x; r[5] = (__bf16)b.y; r[6] = (__bf16)b.z; r[7] = (__bf16)b.w;
  return r;
}

// ---- producer/consumer sync (agent scope, cross-XCD) -----------------------
__device__ __forceinline__ void waitcnt_ge(int* p, int target) {
  if (threadIdx.x == 0) {
    while (__hip_atomic_load(p, __ATOMIC_ACQUIRE, __HIP_MEMORY_SCOPE_AGENT) < target)
      __builtin_amdgcn_s_sleep(1);
  }
  __syncthreads();
}
__device__ __forceinline__ void signal_inc(int* p) {
  __threadfence();   // each thread publishes its writes
  __syncthreads();   // block-level HB into the signaling lane
  if (threadIdx.x == 0)
    __hip_atomic_fetch_add(p, 1, __ATOMIC_RELEASE, __HIP_MEMORY_SCOPE_AGENT);
}

// ---------------------------------------------------------------------------
// k_xmv: xm/xv = x @ Wm[:, :I].T, x @ Wv[:, :I].T -> bf16 into d_out scratch.
// Also zeroes the scan counters. m = t*64+b (16384 rows), n = 512, K = 512.
// ---------------------------------------------------------------------------
__global__ __launch_bounds__(256) void k_xmv(const float* __restrict__ x,
                                             const float* __restrict__ Wm,
                                             const float* __restrict__ Wv,
                                             char* __restrict__ doutc, char* __restrict__ ws) {
  if (blockIdx.x == 0 && blockIdx.y == 0) {
    int* cnt = (int*)(ws + OFF_CNT);
    cnt[threadIdx.x] = 0;
    cnt[threadIdx.x + 256] = 0;
  }
  __bf16* xm = (__bf16*)(doutc + DO_XM);
  __bf16* xv = (__bf16*)(doutc + DO_XV);

  int m0 = blockIdx.x * 64, n0 = blockIdx.y * 64;
  int tid = threadIdx.x, lane = tid & 63, wv = tid >> 6;
  int n15 = lane & 15, q8 = (lane >> 4) * 8;

  int row = m0 + wv * 16 + n15;  // m = t*64 + b
  int t = row >> 6, b = row & 63;
  const float* arow = x + ((size_t)(b * TT + t)) * II + q8;

  const float* brow[4];
#pragma unroll
  for (int j = 0; j < 4; ++j) {
    int c = n0 + j * 16 + n15;
    brow[j] = ((c < SS) ? (Wm + (size_t)c * (II + DD)) : (Wv + (size_t)(c - SS) * (II + DD))) + q8;
  }
  f32x4 acc[4] = {};
#pragma unroll 4
  for (int k = 0; k < II; k += 32) {
    bf16x8 a = ld8f(arow + k);
#pragma unroll
    for (int j = 0; j < 4; ++j) acc[j] = MFMA16(a, ld8f(brow[j] + k), acc[j]);
  }
  int mb = m0 + wv * 16 + (lane >> 4) * 4;
#pragma unroll
  for (int j = 0; j < 4; ++j) {
    int c = n0 + j * 16 + n15;
    __bf16* dst = (c < SS) ? (xm + c) : (xv + (c - SS));
#pragma unroll
    for (int r = 0; r < 4; ++r) dst[(size_t)(mb + r) * SS] = (__bf16)acc[j][r];
  }
}

// ---------------------------------------------------------------------------
// k_scan: persistent. Blocks 0..63 = GRU (16 h-cols each; W_ih + n-gate W_hh
// staged once in LDS as bf16; r/z-gate W_hh streamed fp32 from L2-resident
// global). Blocks 64..79 = posterior (16 z-cols; Wm/Wv h-part streamed).
// Sync: hcnt[t] (64 producers), zcnt[t] (16 producers).
// ---------------------------------------------------------------------------
__global__ __launch_bounds__(256, 1) void k_scan(
    const float* __restrict__ Wih, const float* __restrict__ Whh,
    const float* __restrict__ bih, const float* __restrict__ bhh,
    const float* __restrict__ Wm, const float* __restrict__ bm,
    const float* __restrict__ Wv, const float* __restrict__ bv,
    const float* __restrict__ noise, char* __restrict__ ws, char* __restrict__ doutc) {
  // LDS: [0,12288) W_ih frag-packed [g][kk<8][lane][8]; [12288,28672) W_hh n-gate
  __shared__ __bf16 wl[28672];

  float* hb32[2] = {(float*)(ws + OFF_HB32), (float*)(ws + OFF_HB32) + (size_t)BB * DD};
  __bf16* hb16[2] = {(__bf16*)(ws + OFF_HB16), (__bf16*)(ws + OFF_HB16) + (size_t)BB * DD};
  __bf16* z_cur = (__bf16*)(ws + OFF_ZC);
  __bf16* z_all = (__bf16*)(ws + OFF_Z);
  __bf16* h_all = (__bf16*)doutc;
  const __bf16* xm = (const __bf16*)(doutc + DO_XM);
  const __bf16* xv = (const __bf16*)(doutc + DO_XV);
  int* hcnt = (int*)(ws + OFF_CNT);
  int* zcnt = hcnt + 256;

  int blk = blockIdx.x, tid = threadIdx.x, lane = tid & 63, wv = tid >> 6;
  int n15 = lane & 15, q8 = (lane >> 4) * 8, q4 = (lane >> 4) * 4;
  const int rb = wv * 16 + n15;  // A-fragment batch row

  if (blk < 64) {
    int c0 = blk * 16, cc = c0 + n15;
    // ---- stage W_ih (all gates) + W_hh n-gate into LDS, bf16 frag-packed
    for (int v = tid; v < 1536; v += 256) {
      int lp = v & 63, kk = (v >> 6) & 7, g = v >> 9;
      int col = c0 + (lp & 15), ks = kk * 32 + (lp >> 4) * 8;
      *(bf16x8*)(wl + (size_t)v * 8) = ld8f(Wih + (size_t)(g * DD + col) * SS + ks);
    }
    for (int v = tid; v < 2048; v += 256) {
      int lp = v & 63, kk = v >> 6;
      int col = c0 + (lp & 15), ks = kk * 32 + (lp >> 4) * 8;
      *(bf16x8*)(wl + 12288 + (size_t)v * 8) = ld8f(Whh + (size_t)(2 * DD + col) * DD + ks);
    }
    __syncthreads();

    float brs = bih[cc] + bhh[cc];
    float bzs = bih[DD + cc] + bhh[DD + cc];
    float bin = bih[2 * DD + cc];
    float bhn = bhh[2 * DD + cc];
    const float* whr = Whh + (size_t)(c0 + n15) * DD + q8;
    const float* whz = Whh + (size_t)(DD + c0 + n15) * DD + q8;

    for (int t = 0; t < TT; ++t) {
      f32x4 accr = {}, accz = {}, acchn = {}, accin = {};
      if (t > 0) {
        waitcnt_ge(&hcnt[t - 1], 64);  // h_{t-1} ready (all 1024 cols)
        const __bf16* aptr = hb16[t & 1] + (size_t)rb * DD + q8;
#pragma unroll 4
        for (int kk = 0; kk < 32; ++kk) {
          bf16x8 a = *(const bf16x8*)(aptr + kk * 32);
          accr = MFMA16(a, ld8f(whr + kk * 32), accr);
          accz = MFMA16(a, ld8f(whz + kk * 32), accz);
          acchn = MFMA16(a, *(const bf16x8*)(wl + 12288 + ((size_t)kk * 64 + lane) * 8), acchn);
        }
        waitcnt_ge(&zcnt[t - 1], 16);  // z_{t-1} ready
        const __bf16* zptr = z_cur + (size_t)rb * SS + q8;
#pragma unroll
        for (int kk = 0; kk < 8; ++kk) {
          bf16x8 a = *(const bf16x8*)(zptr + kk * 32);
          accr = MFMA16(a, *(const bf16x8*)(wl + ((size_t)(0 * 8 + kk) * 64 + lane) * 8), accr);
          accz = MFMA16(a, *(const bf16x8*)(wl + ((size_t)(1 * 8 + kk) * 64 + lane) * 8), accz);
          accin = MFMA16(a, *(const bf16x8*)(wl + ((size_t)(2 * 8 + kk) * 64 + lane) * 8), accin);
        }
      }
      const float* ho32 = hb32[t & 1];
      float* hn32 = hb32[(t + 1) & 1];
      __bf16* hn16 = hb16[(t + 1) & 1];
      __bf16* hall_t = h_all + (size_t)t * BB * DD;
      int mb = wv * 16 + q4;
#pragma unroll
      for (int r = 0; r < 4; ++r) {
        int mm = mb + r;
        float rg = fsig(accr[r] + brs);
        float zg = fsig(accz[r] + bzs);
        float ng = ftanh(accin[r] + bin + rg * (acchn[r] + bhn));
        float ho = (t > 0) ? ho32[mm * DD + cc] : 0.f;
        float hn = (1.f - zg) * ng + zg * ho;
        hn32[mm * DD + cc] = hn;
        __bf16 hbv = (__bf16)hn;
        hn16[mm * DD + cc] = hbv;
        hall_t[(size_t)mm * DD + cc] = hbv;
      }
      signal_inc(&hcnt[t]);
    }
  } else {
    int p = blk - 64, c2 = p * 16 + n15;
    float bmv = bm[c2], bvv = bv[c2];
    const float* wmh = Wm + (size_t)c2 * (II + DD) + II + q8;
    const float* wvh = Wv + (size_t)c2 * (II + DD) + II + q8;

    for (int t = 0; t < TT; ++t) {
      waitcnt_ge(&hcnt[t], 64);  // h_t ready
      f32x4 am = {}, av = {};
      const __bf16* hptr = hb16[(t + 1) & 1] + (size_t)rb * DD + q8;
#pragma unroll 4
      for (int kk = 0; kk < 32; ++kk) {
        bf16x8 a = *(const bf16x8*)(hptr + kk * 32);
        am = MFMA16(a, ld8f(wmh + kk * 32), am);
        av = MFMA16(a, ld8f(wvh + kk * 32), av);
      }
      int mb = wv * 16 + q4;
#pragma unroll
      for (int r = 0; r < 4; ++r) {
        int mm = mb + r;
        size_t gidx = ((size_t)t * BB + mm) * SS + c2;
        float mean = am[r] + bmv + (float)xm[gidx];
        float vr = av[r] + bvv + (float)xv[gidx];
        float sd = __expf(0.5f * vr);
        float zt = noise[gidx] * sd + mean;
        __bf16 zb = (__bf16)zt;
        z_cur[mm * SS + c2] = zb;
        z_all[gidx] = zb;
      }
      signal_inc(&zcnt[t]);
    }
  }
}

// ---------------------------------------------------------------------------
// Decoder layer 0: elu([h_all | z_all] @ W0.T + b0) -> a0 (ws), K=1280
// ---------------------------------------------------------------------------
__global__ __launch_bounds__(256, 2) void k_dec0(const char* __restrict__ doutc,
                                                 const char* __restrict__ ws,
                                                 const float* __restrict__ W0,
                                                 const float* __restrict__ b0,
                                                 __bf16* __restrict__ C) {
  const __bf16* h_all = (const __bf16*)doutc;
  const __bf16* z_all = (const __bf16*)(ws + OFF_Z);
  int m0 = blockIdx.x * 128, n0 = blockIdx.y * 128;
  int tid = threadIdx.x, lane = tid & 63, w = tid >> 6;
  int wm = w >> 1, wn = w & 1;
  int n15 = lane & 15, q8 = (lane >> 4) * 8, q4 = (lane >> 4) * 4;

  const __bf16* hrow[4];
  const __bf16* zrow[4];
  const float* brow[4];
#pragma unroll
  for (int i = 0; i < 4; ++i) {
    int row = m0 + wm * 64 + i * 16 + n15;  // m = b*256 + t
    int b = row >> 8, tq = row & 255;
    hrow[i] = h_all + ((size_t)tq * BB + b) * DD + q8;
    zrow[i] = z_all + ((size_t)tq * BB + b) * SS + q8;
  }
#pragma unroll
  for (int j = 0; j < 4; ++j)
    brow[j] = W0 + (size_t)(n0 + wn * 64 + j * 16 + n15) * (DD + SS) + q8;

  f32x4 acc[4][4] = {};
  for (int k = 0; k < DD + SS; k += 32) {
    bf16x8 af[4], bfv[4];
#pragma unroll
    for (int i = 0; i < 4; ++i)
      af[i] = (k < DD) ? *(const bf16x8*)(hrow[i] + k) : *(const bf16x8*)(zrow[i] + k - DD);
#pragma unroll
    for (int j = 0; j < 4; ++j) bfv[j] = ld8f(brow[j] + k);
#pragma unroll
    for (int i = 0; i < 4; ++i)
#pragma unroll
      for (int j = 0; j < 4; ++j) acc[i][j] = MFMA16(af[i], bfv[j], acc[i][j]);
  }
#pragma unroll
  for (int i = 0; i < 4; ++i) {
    int mr = m0 + wm * 64 + i * 16 + q4;
#pragma unroll
    for (int j = 0; j < 4; ++j) {
      int c = n0 + wn * 64 + j * 16 + n15;
      float bb = b0[c];
#pragma unroll
      for (int r = 0; r < 4; ++r) {
        float v = acc[i][j][r] + bb;
        v = v > 0.f ? v : (__expf(v) - 1.f);
        C[(size_t)(mr + r) * HH + c] = (__bf16)v;
      }
    }
  }
}

// ---------------------------------------------------------------------------
// Decoder mid layer: C = elu(A @ W.T + b), K = N = 1024, contiguous bf16 A/C
// ---------------------------------------------------------------------------
__global__ __launch_bounds__(256, 2) void k_dec_mid(const __bf16* __restrict__ A,
                                                    const float* __restrict__ W,
                                                    const float* __restrict__ bias,
                                                    __bf16* __restrict__ C) {
  int m0 = blockIdx.x * 128, n0 = blockIdx.y * 128;
  int tid = threadIdx.x, lane = tid & 63, w = tid >> 6;
  int wm = w >> 1, wn = w & 1;
  int n15 = lane & 15, q8 = (lane >> 4) * 8, q4 = (lane >> 4) * 4;

  const __bf16* arow[4];
  const float* brow[4];
#pragma unroll
  for (int i = 0; i < 4; ++i) arow[i] = A + (size_t)(m0 + wm * 64 + i * 16 + n15) * DD + q8;
#pragma unroll
  for (int j = 0; j < 4; ++j) brow[j] = W + (size_t)(n0 + wn * 64 + j * 16 + n15) * DD + q8;

  f32x4 acc[4][4] = {};
  for (int k = 0; k < DD; k += 32) {
    bf16x8 af[4], bfv[4];
#pragma unroll
    for (int i = 0; i < 4; ++i) af[i] = *(const bf16x8*)(arow[i] + k);
#pragma unroll
    for (int j = 0; j < 4; ++j) bfv[j] = ld8f(brow[j] + k);
#pragma unroll
    for (int i = 0; i < 4; ++i)
#pragma unroll
      for (int j = 0; j < 4; ++j) acc[i][j] = MFMA16(af[i], bfv[j], acc[i][j]);
  }
#pragma unroll
  for (int i = 0; i < 4; ++i) {
    int mr = m0 + wm * 64 + i * 16 + q4;
#pragma unroll
    for (int j = 0; j < 4; ++j) {
      int c = n0 + wn * 64 + j * 16 + n15;
      float bb = bias[c];
#pragma unroll
      for (int r = 0; r < 4; ++r) {
        float v = acc[i][j][r] + bb;
        v = v > 0.f ? v : (__expf(v) - 1.f);
        C[(size_t)(mr + r) * HH + c] = (__bf16)v;
      }
    }
  }
}

// ---------------------------------------------------------------------------
// Decoder layer 3 + output assembly (fp32 outputs):
// outd[b,t,:] = d (t<255); outh[b,0,:] = x[b,0,:]; outh[b,t+1,:] = x[b,t,:]+d
// ---------------------------------------------------------------------------
__global__ __launch_bounds__(256, 2) void k_dec3(const __bf16* __restrict__ A,
                                                 const float* __restrict__ W3,
                                                 const float* __restrict__ b3,
                                                 const float* __restrict__ x,
                                                 float* __restrict__ outd,
                                                 float* __restrict__ outh) {
  int m0 = blockIdx.x * 128, n0 = blockIdx.y * 128;
  int tid = threadIdx.x, lane = tid & 63, w = tid >> 6;
  int wm = w >> 1, wn = w & 1;
  int n15 = lane & 15, q8 = (lane >> 4) * 8, q4 = (lane >> 4) * 4;

  const __bf16* arow[4];
  const float* brow[4];
#pragma unroll
  for (int i = 0; i < 4; ++i) arow[i] = A + (size_t)(m0 + wm * 64 + i * 16 + n15) * HH + q8;
#pragma unroll
  for (int j = 0; j < 4; ++j) brow[j] = W3 + (size_t)(n0 + wn * 64 + j * 16 + n15) * HH + q8;

  f32x4 acc[4][4] = {};
  for (int k = 0; k < HH; k += 32) {
    bf16x8 af[4], bfv[4];
#pragma unroll
    for (int i = 0; i < 4; ++i) af[i] = *(const bf16x8*)(arow[i] + k);
#pragma unroll
    for (int j = 0; j < 4; ++j) bfv[j] = ld8f(brow[j] + k);
#pragma unroll
    for (int i = 0; i < 4; ++i)
#pragma unroll
      for (int j = 0; j < 4; ++j) acc[i][j] = MFMA16(af[i], bfv[j], acc[i][j]);
  }
#pragma unroll
  for (int i = 0; i < 4; ++i) {
    int mr = m0 + wm * 64 + i * 16 + q4;
#pragma unroll
    for (int j = 0; j < 4; ++j) {
      int c = n0 + wn * 64 + j * 16 + n15;
      float b3v = b3[c];
#pragma unroll
      for (int r = 0; r < 4; ++r) {
        int mm = mr + r;
        int b = mm >> 8, tq = mm & 255;
        float dv = acc[i][j][r] + b3v;
        if (tq < 255) {
          outd[((size_t)b * 255 + tq) * II + c] = dv;
          outh[((size_t)b * TT + tq + 1) * II + c] = x[((size_t)b * TT + tq) * II + c] + dv;
        }
        if (tq == 0) outh[((size_t)b * TT) * II + c] = x[((size_t)b * TT) * II + c];
      }
    }
  }
}

// ---------------------------------------------------------------------------
extern "C" void kernel_launch(void* const* d_in, const int* in_sizes, int n_in,
                              void* d_out, int out_size, void* d_ws, size_t ws_size,
                              hipStream_t stream) {
  const float* x = (const float*)d_in[0];
  const float* noise = (const float*)d_in[1];
  const float* W_ih = (const float*)d_in[2];
  const float* W_hh = (const float*)d_in[3];
  const float* b_ih = (const float*)d_in[4];
  const float* b_hh = (const float*)d_in[5];
  const float* Wm = (const float*)d_in[6];
  const float* bm = (const float*)d_in[7];
  const float* Wv = (const float*)d_in[8];
  const float* bv = (const float*)d_in[9];
  const float* dW0 = (const float*)d_in[10];
  const float* db0 = (const float*)d_in[11];
  const float* dW1 = (const float*)d_in[12];
  const float* db1 = (const float*)d_in[13];
  const float* dW2 = (const float*)d_in[14];
  const float* db2 = (const float*)d_in[15];
  const float* dW3 = (const float*)d_in[16];
  const float* db3 = (const float*)d_in[17];

  char* ws = (char*)d_ws;
  char* doutc = (char*)d_out;
  __bf16* a0 = (__bf16*)(ws + OFF_A);       // dec0 out
  __bf16* a1 = (__bf16*)doutc;              // dec1 out (over dead h_all)
  __bf16* a2 = (__bf16*)(ws + OFF_A);       // dec2 out (over dead a0)

  // 1) x-dependent posterior halves (bf16, into d_out scratch) + zero counters
  k_xmv<<<dim3(256, 8), 256, 0, stream>>>(x, Wm, Wv, doutc, ws);

  // 2) persistent sequential scan (single launch, producer/consumer sync)
  k_scan<<<80, 256, 0, stream>>>(W_ih, W_hh, b_ih, b_hh, Wm, bm, Wv, bv, noise, ws, doutc);

  // 3) decoder
  k_dec0<<<dim3(128, 8), 256, 0, stream>>>(doutc, ws, dW0, db0, a0);
  k_dec_mid<<<dim3(128, 8), 256, 0, stream>>>(a0, dW1, db1, a1);
  k_dec_mid<<<dim3(128, 8), 256, 0, stream>>>(a1, dW2, db2, a2);
  k_dec3<<<dim3(128, 4), 256, 0, stream>>>(a2, dW3, db3, x, (float*)doutc,
                                           (float*)doutc + OUTD_ELEMS);
}